// Round 3
// baseline (1223.080 us; speedup 1.0000x reference)
//
#include <hip/hip_runtime.h>
#include <stdint.h>

#define C_HID 128
#define NGRAPH 64
#define COUT 64

typedef short bf16x8 __attribute__((ext_vector_type(8)));
typedef float f32x4 __attribute__((ext_vector_type(4)));

__device__ __forceinline__ float bf2f(unsigned short h){
  unsigned int u = ((unsigned int)h) << 16;
  return __builtin_bit_cast(float, u);
}
__device__ __forceinline__ unsigned short f2bf(float f){
  unsigned int u = __builtin_bit_cast(unsigned int, f);
  u = u + 0x7FFFu + ((u >> 16) & 1u);   // RNE
  return (unsigned short)(u >> 16);
}
__device__ __forceinline__ int clampi(int v, int lo, int hi){
  return v < lo ? lo : (v > hi ? hi : v);
}

__global__ void k_zero(float* __restrict__ out, int n){
  int i = blockIdx.x*blockDim.x + threadIdx.x;
  if (i < n) out[i] = 0.f;
}

// ---------- CSR build ----------
__global__ void k_hist(const int* __restrict__ dst, int* __restrict__ counts, int E, int N){
  int e = blockIdx.x*blockDim.x + threadIdx.x;
  if (e < E) atomicAdd(&counts[clampi(dst[e], 0, N-1)], 1);
}

__global__ void k_dinv(const int* __restrict__ counts, float* __restrict__ dinv, int N){
  int i = blockIdx.x*blockDim.x + threadIdx.x;
  if (i < N) dinv[i] = rsqrtf((float)(counts[i] + 1));  // +1 = self loop
}

__global__ void k_scan1(const int* __restrict__ counts, int* __restrict__ bsum, int N){
  __shared__ int red[512];
  int i = blockIdx.x*512 + threadIdx.x;
  red[threadIdx.x] = (i < N) ? counts[i] : 0;
  __syncthreads();
  for (int off = 256; off > 0; off >>= 1){
    if (threadIdx.x < off) red[threadIdx.x] += red[threadIdx.x + off];
    __syncthreads();
  }
  if (threadIdx.x == 0) bsum[blockIdx.x] = red[0];
}

// single block, NB <= 256
__global__ void k_scan2(const int* __restrict__ bsum, int* __restrict__ boff,
                        int* __restrict__ offs, int NB, int N){
  __shared__ int buf[256];
  int t = threadIdx.x;
  int v = (t < NB) ? bsum[t] : 0;
  buf[t] = v; __syncthreads();
  for (int off = 1; off < 256; off <<= 1){
    int add = (t >= off) ? buf[t-off] : 0;
    __syncthreads();
    buf[t] += add;
    __syncthreads();
  }
  if (t < NB) boff[t] = buf[t] - v;          // exclusive
  if (t == NB-1) offs[N] = buf[t];           // total == E
}

__global__ void k_scan3(const int* __restrict__ counts, const int* __restrict__ boff,
                        int* __restrict__ offs, int N){
  __shared__ int buf[512];
  int t = threadIdx.x; int i = blockIdx.x*512 + t;
  int v = (i < N) ? counts[i] : 0;
  buf[t] = v; __syncthreads();
  for (int off = 1; off < 512; off <<= 1){
    int add = (t >= off) ? buf[t-off] : 0;
    __syncthreads();
    buf[t] += add;
    __syncthreads();
  }
  if (i < N) offs[i] = boff[blockIdx.x] + buf[t] - v;  // exclusive prefix
}

__global__ void k_fill(const int* __restrict__ src, const int* __restrict__ dst,
                       const float* __restrict__ dinv, const int* __restrict__ offs,
                       int* __restrict__ cursor, int* __restrict__ src_s,
                       float* __restrict__ nrm_s, int E, int N){
  int e = blockIdx.x*blockDim.x + threadIdx.x;
  if (e >= E) return;
  int d = clampi(dst[e], 0, N-1);
  int s = clampi(src[e], 0, N-1);
  int pos = offs[d] + atomicAdd(&cursor[d], 1);
  pos = clampi(pos, 0, E-1);
  src_s[pos] = s;
  nrm_s[pos] = dinv[s] * dinv[d];
}

// ---------- SpMM: agg[i] = sum_e norm_e * x[src_e] + dinv[i]^2 * x[i] ----------
// one wave per node; lane owns channels (2*lane, 2*lane+1); fp32 accumulate.
// FP32IN: x is float [N][128]; else packed bf16 pairs (uint) [N][64].
// Output: packed bf16 pairs.
template<bool FP32IN>
__global__ void k_spmm(const void* __restrict__ xin, const int* __restrict__ offs,
                       const int* __restrict__ srcs, const float* __restrict__ nrms,
                       const float* __restrict__ dinv, unsigned int* __restrict__ agg,
                       int N, int E){
  int gid = blockIdx.x*blockDim.x + threadIdx.x;
  int node = gid >> 6;
  int lane = gid & 63;
  if (node >= N) return;
  const float2* xf = (const float2*)xin;
  const unsigned int* xu = (const unsigned int*)xin;
  int e0 = clampi(offs[node], 0, E);
  int e1 = clampi(offs[node+1], e0, E);
  float ax = 0.f, ay = 0.f;
  for (int e = e0; e < e1; ++e){
    int s = clampi(srcs[e], 0, N-1);   // wave-uniform
    float nr = nrms[e];
    if (FP32IN){
      float2 v = xf[(size_t)s*64 + lane];
      ax += nr * v.x;
      ay += nr * v.y;
    } else {
      unsigned int u = xu[(size_t)s*64 + lane];
      ax += nr * __builtin_bit_cast(float, u << 16);
      ay += nr * __builtin_bit_cast(float, u & 0xFFFF0000u);
    }
  }
  float di = dinv[node];
  float nr = di * di;                // self loop
  if (FP32IN){
    float2 v = xf[(size_t)node*64 + lane];
    ax += nr * v.x;
    ay += nr * v.y;
  } else {
    unsigned int u = xu[(size_t)node*64 + lane];
    ax += nr * __builtin_bit_cast(float, u << 16);
    ay += nr * __builtin_bit_cast(float, u & 0xFFFF0000u);
  }
  agg[(size_t)node*64 + lane] = (unsigned int)f2bf(ax) | ((unsigned int)f2bf(ay) << 16);
}

// ---------- GEMM: out = relu(A[Mx128] @ W[128x128] + b) ----------
// A: bf16 [M][128]; W,b: fp32; out: bf16. bf16 MFMA, fp32 accumulate.
// block = 4 waves, 64 rows/block; W^T in LDS (stride 136 -> benign 2-way conflicts)
__global__ __launch_bounds__(256) void k_gemm(const unsigned short* __restrict__ A,
                                              const float* __restrict__ W,
                                              const float* __restrict__ bias,
                                              unsigned short* __restrict__ out, int M){
  __shared__ unsigned short wt[128*136];
  for (int idx = threadIdx.x; idx < 128*128; idx += 256){
    int k = idx >> 7, n = idx & 127;
    wt[n*136 + k] = f2bf(W[idx]);    // Wt[n][k] = bf16(W[k][n])
  }
  __syncthreads();

  int wv = threadIdx.x >> 6, lane = threadIdx.x & 63;
  int q = lane >> 4, ln = lane & 15;
  int m0 = blockIdx.x*64 + wv*16;
  int arow = m0 + ln;
  bool arow_ok = (arow < M);
  if (!arow_ok) arow = 0;            // safe address; fragment zeroed below

  f32x4 zero = {0.f, 0.f, 0.f, 0.f};
  f32x4 acc[8];
  #pragma unroll
  for (int t = 0; t < 8; ++t) acc[t] = zero;

  #pragma unroll
  for (int kk = 0; kk < 4; ++kk){
    // A-frag: A[m = lane&15][k = kk*32 + q*8 + j]
    bf16x8 a;
    if (arow_ok){
      __builtin_memcpy(&a, A + (size_t)arow*128 + kk*32 + q*8, 16);
    } else {
      a = (bf16x8){0,0,0,0,0,0,0,0};
    }
    #pragma unroll
    for (int t = 0; t < 8; ++t){
      // B-frag: B[k][n = t*16 + ln] == Wt[n][k], contiguous in k
      bf16x8 b;
      __builtin_memcpy(&b, &wt[(t*16 + ln)*136 + kk*32 + q*8], 16);
      acc[t] = __builtin_amdgcn_mfma_f32_16x16x32_bf16(a, b, acc[t], 0, 0, 0);
    }
  }
  // D: row = m0 + q*4 + r, col = t*16 + ln
  #pragma unroll
  for (int t = 0; t < 8; ++t){
    float bv = bias[t*16 + ln];
    #pragma unroll
    for (int r = 0; r < 4; ++r){
      int row = m0 + q*4 + r;
      if (row < M){
        float v = acc[t][r] + bv;
        v = v > 0.f ? v : 0.f;
        out[(size_t)row*128 + t*16 + ln] = f2bf(v);
      }
    }
  }
}

// ---------- fused mean-pool + linear head (fp32 out) ----------
__device__ __forceinline__ int lower_bound_i(const int* arr, int n, int val){
  int lo = 0, hi = n;
  while (lo < hi){ int mid = (lo + hi) >> 1; if (arr[mid] < val) lo = mid + 1; else hi = mid; }
  return lo;
}

// grid = NGRAPH blocks of 128 threads (thread = channel for pooling)
__global__ void k_head(const unsigned short* __restrict__ x, const int* __restrict__ batch,
                       const float* __restrict__ Wl, const float* __restrict__ bl,
                       float* __restrict__ out, int N){
  __shared__ float sums[C_HID];
  int g = blockIdx.x;
  int t = threadIdx.x;
  int s = clampi(lower_bound_i(batch, N, g), 0, N);
  int e = clampi(lower_bound_i(batch, N, g + 1), s, N);
  float acc = 0.f;
  for (int i = s; i < e; ++i) acc += bf2f(x[(size_t)i*C_HID + t]);
  sums[t] = acc;
  __syncthreads();
  if (t < COUT){
    float inv = 1.0f / fmaxf((float)(e - s), 1.0f);
    float o = 0.f;
    for (int k = 0; k < C_HID; ++k)
      o += sums[k] * Wl[k*COUT + t];
    out[g*COUT + t] = o * inv + bl[t];
  }
}

extern "C" void kernel_launch(void* const* d_in, const int* in_sizes, int n_in,
                              void* d_out, int out_size, void* d_ws, size_t ws_size,
                              hipStream_t stream){
  const float* x0 = (const float*)d_in[0];
  const int* ei   = (const int*)d_in[1];
  const int* batch= (const int*)d_in[2];
  const float* W1 = (const float*)d_in[3];
  const float* b1 = (const float*)d_in[4];
  const float* W2 = (const float*)d_in[5];
  const float* b2 = (const float*)d_in[6];
  const float* W3 = (const float*)d_in[7];
  const float* b3 = (const float*)d_in[8];
  const float* Wl = (const float*)d_in[9];
  const float* bl = (const float*)d_in[10];
  float* out = (float*)d_out;

  int E = in_sizes[1] / 2;
  int N = in_sizes[2];
  const int* src = ei;
  const int* dst = ei + E;

  // workspace layout (256B-aligned slots)
  size_t off_acc = 0;
  auto carve = [&](size_t bytes)->size_t{
    size_t r = off_acc; off_acc += (bytes + 255) & ~(size_t)255; return r;
  };
  size_t o_counts = carve((size_t)N*4);
  size_t o_cursor = carve((size_t)N*4);
  size_t o_offs   = carve((size_t)(N+1)*4);
  size_t o_bsum   = carve(256*4);
  size_t o_boff   = carve(256*4);
  size_t o_dinv   = carve((size_t)N*4);
  size_t o_srcs   = carve((size_t)E*4);
  size_t o_nrms   = carve((size_t)E*4);
  size_t o_aggb   = carve((size_t)N*C_HID*2);   // bf16
  size_t o_xbuf   = carve((size_t)N*C_HID*2);   // bf16
  size_t need = off_acc;

  if (ws_size < need){
    // diagnostic fallback: zero output (absmax would read exactly max|ref| = 1.167e-1)
    k_zero<<<(out_size+255)/256, 256, 0, stream>>>(out, out_size);
    return;
  }

  char* base = (char*)d_ws;
  int* counts   = (int*)(base + o_counts);
  int* cursor   = (int*)(base + o_cursor);
  int* offs     = (int*)(base + o_offs);
  int* bsum     = (int*)(base + o_bsum);
  int* boff     = (int*)(base + o_boff);
  float* dinv   = (float*)(base + o_dinv);
  int* src_s    = (int*)(base + o_srcs);
  float* nrm_s  = (float*)(base + o_nrms);
  unsigned int* aggb   = (unsigned int*)(base + o_aggb);
  unsigned short* xbuf = (unsigned short*)(base + o_xbuf);

  hipMemsetAsync(counts, 0, (size_t)N*4, stream);
  hipMemsetAsync(cursor, 0, (size_t)N*4, stream);

  int NB = (N + 511) / 512;
  k_hist <<<(E+255)/256, 256, 0, stream>>>(dst, counts, E, N);
  k_dinv <<<(N+255)/256, 256, 0, stream>>>(counts, dinv, N);
  k_scan1<<<NB, 512, 0, stream>>>(counts, bsum, N);
  k_scan2<<<1, 256, 0, stream>>>(bsum, boff, offs, NB, N);
  k_scan3<<<NB, 512, 0, stream>>>(counts, boff, offs, N);
  k_fill <<<(E+255)/256, 256, 0, stream>>>(src, dst, dinv, offs, cursor, src_s, nrm_s, E, N);

  int spmm_grid = (N + 3) / 4;     // 4 waves/block, one wave per node
  int gemm_grid = (N + 63) / 64;   // 64 rows/block

  k_spmm<true ><<<spmm_grid, 256, 0, stream>>>(x0, offs, src_s, nrm_s, dinv, aggb, N, E);
  k_gemm<<<gemm_grid, 256, 0, stream>>>((const unsigned short*)aggb, W1, b1, xbuf, N);
  k_spmm<false><<<spmm_grid, 256, 0, stream>>>(xbuf, offs, src_s, nrm_s, dinv, aggb, N, E);
  k_gemm<<<gemm_grid, 256, 0, stream>>>((const unsigned short*)aggb, W2, b2, xbuf, N);
  k_spmm<false><<<spmm_grid, 256, 0, stream>>>(xbuf, offs, src_s, nrm_s, dinv, aggb, N, E);
  k_gemm<<<gemm_grid, 256, 0, stream>>>((const unsigned short*)aggb, W3, b3, xbuf, N);

  k_head<<<NGRAPH, 128, 0, stream>>>(xbuf, batch, Wl, bl, out, N);
}

// Round 4
// 842.155 us; speedup vs baseline: 1.4523x; 1.4523x over previous
//
#include <hip/hip_runtime.h>
#include <stdint.h>

#define C_HID 128
#define NGRAPH 64
#define COUT 64
#define POOL_S 64   // chunks per graph

typedef short bf16x8 __attribute__((ext_vector_type(8)));
typedef float f32x4 __attribute__((ext_vector_type(4)));

__device__ __forceinline__ float bf2f(unsigned short h){
  unsigned int u = ((unsigned int)h) << 16;
  return __builtin_bit_cast(float, u);
}
__device__ __forceinline__ unsigned short f2bf(float f){
  unsigned int u = __builtin_bit_cast(unsigned int, f);
  u = u + 0x7FFFu + ((u >> 16) & 1u);   // RNE
  return (unsigned short)(u >> 16);
}
__device__ __forceinline__ int clampi(int v, int lo, int hi){
  return v < lo ? lo : (v > hi ? hi : v);
}

__global__ void k_zero(float* __restrict__ out, int n){
  int i = blockIdx.x*blockDim.x + threadIdx.x;
  if (i < n) out[i] = 0.f;
}

// ---------- CSR build ----------
__global__ void k_hist(const int* __restrict__ dst, int* __restrict__ counts, int E, int N){
  int e = blockIdx.x*blockDim.x + threadIdx.x;
  if (e < E) atomicAdd(&counts[clampi(dst[e], 0, N-1)], 1);
}

__global__ void k_dinv(const int* __restrict__ counts, float* __restrict__ dinv, int N){
  int i = blockIdx.x*blockDim.x + threadIdx.x;
  if (i < N) dinv[i] = rsqrtf((float)(counts[i] + 1));  // +1 = self loop
}

__global__ void k_scan1(const int* __restrict__ counts, int* __restrict__ bsum, int N){
  __shared__ int red[512];
  int i = blockIdx.x*512 + threadIdx.x;
  red[threadIdx.x] = (i < N) ? counts[i] : 0;
  __syncthreads();
  for (int off = 256; off > 0; off >>= 1){
    if (threadIdx.x < off) red[threadIdx.x] += red[threadIdx.x + off];
    __syncthreads();
  }
  if (threadIdx.x == 0) bsum[blockIdx.x] = red[0];
}

// single block, NB <= 256
__global__ void k_scan2(const int* __restrict__ bsum, int* __restrict__ boff,
                        int* __restrict__ offs, int NB, int N){
  __shared__ int buf[256];
  int t = threadIdx.x;
  int v = (t < NB) ? bsum[t] : 0;
  buf[t] = v; __syncthreads();
  for (int off = 1; off < 256; off <<= 1){
    int add = (t >= off) ? buf[t-off] : 0;
    __syncthreads();
    buf[t] += add;
    __syncthreads();
  }
  if (t < NB) boff[t] = buf[t] - v;          // exclusive
  if (t == NB-1) offs[N] = buf[t];           // total == E
}

__global__ void k_scan3(const int* __restrict__ counts, const int* __restrict__ boff,
                        int* __restrict__ offs, int N){
  __shared__ int buf[512];
  int t = threadIdx.x; int i = blockIdx.x*512 + t;
  int v = (i < N) ? counts[i] : 0;
  buf[t] = v; __syncthreads();
  for (int off = 1; off < 512; off <<= 1){
    int add = (t >= off) ? buf[t-off] : 0;
    __syncthreads();
    buf[t] += add;
    __syncthreads();
  }
  if (i < N) offs[i] = boff[blockIdx.x] + buf[t] - v;  // exclusive prefix
}

__global__ void k_fill(const int* __restrict__ src, const int* __restrict__ dst,
                       const float* __restrict__ dinv, const int* __restrict__ offs,
                       int* __restrict__ cursor, int* __restrict__ src_s,
                       float* __restrict__ nrm_s, int E, int N){
  int e = blockIdx.x*blockDim.x + threadIdx.x;
  if (e >= E) return;
  int d = clampi(dst[e], 0, N-1);
  int s = clampi(src[e], 0, N-1);
  int pos = offs[d] + atomicAdd(&cursor[d], 1);
  pos = clampi(pos, 0, E-1);
  src_s[pos] = s;
  nrm_s[pos] = dinv[s] * dinv[d];
}

// ---------- SpMM: agg[i] = sum_e norm_e * x[src_e] + dinv[i]^2 * x[i] ----------
// one wave per node; lane owns channels (2*lane, 2*lane+1); fp32 accumulate.
// FP32IN: x is float [N][128]; else packed bf16 pairs (uint) [N][64].
template<bool FP32IN>
__global__ void k_spmm(const void* __restrict__ xin, const int* __restrict__ offs,
                       const int* __restrict__ srcs, const float* __restrict__ nrms,
                       const float* __restrict__ dinv, unsigned int* __restrict__ agg,
                       int N, int E){
  int gid = blockIdx.x*blockDim.x + threadIdx.x;
  int node = gid >> 6;
  int lane = gid & 63;
  if (node >= N) return;
  const float2* xf = (const float2*)xin;
  const unsigned int* xu = (const unsigned int*)xin;
  int e0 = clampi(offs[node], 0, E);
  int e1 = clampi(offs[node+1], e0, E);
  float ax = 0.f, ay = 0.f;
  for (int e = e0; e < e1; ++e){
    int s = clampi(srcs[e], 0, N-1);   // wave-uniform
    float nr = nrms[e];
    if (FP32IN){
      float2 v = xf[(size_t)s*64 + lane];
      ax += nr * v.x;
      ay += nr * v.y;
    } else {
      unsigned int u = xu[(size_t)s*64 + lane];
      ax += nr * __builtin_bit_cast(float, u << 16);
      ay += nr * __builtin_bit_cast(float, u & 0xFFFF0000u);
    }
  }
  float di = dinv[node];
  float nr = di * di;                // self loop
  if (FP32IN){
    float2 v = xf[(size_t)node*64 + lane];
    ax += nr * v.x;
    ay += nr * v.y;
  } else {
    unsigned int u = xu[(size_t)node*64 + lane];
    ax += nr * __builtin_bit_cast(float, u << 16);
    ay += nr * __builtin_bit_cast(float, u & 0xFFFF0000u);
  }
  agg[(size_t)node*64 + lane] = (unsigned int)f2bf(ax) | ((unsigned int)f2bf(ay) << 16);
}

// ---------- GEMM: out = relu(A[Mx128] @ W[128x128] + b) ----------
// A: bf16 [M][128]; W,b: fp32; out: bf16. bf16 MFMA, fp32 accumulate.
// block = 4 waves, 64 rows/block; W^T in LDS (stride 136 -> benign 2-way conflicts)
__global__ __launch_bounds__(256) void k_gemm(const unsigned short* __restrict__ A,
                                              const float* __restrict__ W,
                                              const float* __restrict__ bias,
                                              unsigned short* __restrict__ out, int M){
  __shared__ unsigned short wt[128*136];
  for (int idx = threadIdx.x; idx < 128*128; idx += 256){
    int k = idx >> 7, n = idx & 127;
    wt[n*136 + k] = f2bf(W[idx]);    // Wt[n][k] = bf16(W[k][n])
  }
  __syncthreads();

  int wv = threadIdx.x >> 6, lane = threadIdx.x & 63;
  int q = lane >> 4, ln = lane & 15;
  int m0 = blockIdx.x*64 + wv*16;
  int arow = m0 + ln;
  bool arow_ok = (arow < M);
  if (!arow_ok) arow = 0;            // safe address; fragment zeroed below

  f32x4 zero = {0.f, 0.f, 0.f, 0.f};
  f32x4 acc[8];
  #pragma unroll
  for (int t = 0; t < 8; ++t) acc[t] = zero;

  #pragma unroll
  for (int kk = 0; kk < 4; ++kk){
    // A-frag: A[m = lane&15][k = kk*32 + q*8 + j]
    bf16x8 a;
    if (arow_ok){
      __builtin_memcpy(&a, A + (size_t)arow*128 + kk*32 + q*8, 16);
    } else {
      a = (bf16x8){0,0,0,0,0,0,0,0};
    }
    #pragma unroll
    for (int t = 0; t < 8; ++t){
      // B-frag: B[k][n = t*16 + ln] == Wt[n][k], contiguous in k
      bf16x8 b;
      __builtin_memcpy(&b, &wt[(t*16 + ln)*136 + kk*32 + q*8], 16);
      acc[t] = __builtin_amdgcn_mfma_f32_16x16x32_bf16(a, b, acc[t], 0, 0, 0);
    }
  }
  // D: row = m0 + q*4 + r, col = t*16 + ln
  #pragma unroll
  for (int t = 0; t < 8; ++t){
    float bv = bias[t*16 + ln];
    #pragma unroll
    for (int r = 0; r < 4; ++r){
      int row = m0 + q*4 + r;
      if (row < M){
        float v = acc[t][r] + bv;
        v = v > 0.f ? v : 0.f;
        out[(size_t)row*128 + t*16 + ln] = f2bf(v);
      }
    }
  }
}

// ---------- pooling ----------
__device__ __forceinline__ int lower_bound_i(const int* arr, int n, int val){
  int lo = 0, hi = n;
  while (lo < hi){ int mid = (lo + hi) >> 1; if (arr[mid] < val) lo = mid + 1; else hi = mid; }
  return lo;
}

// grid = NGRAPH*POOL_S blocks, 128 threads.
// Block (g,s) sums its chunk of graph g into partial[(g*POOL_S+s)*2+half][128].
// Thread = (half, channel-pair): half h handles rows a+h, a+h+2, ...
__global__ void k_pool(const unsigned int* __restrict__ x, const int* __restrict__ batch,
                       float* __restrict__ partial, int N){
  int g = blockIdx.x / POOL_S, s = blockIdx.x % POOL_S;
  int h = threadIdx.x >> 6;         // 0/1
  int lane = threadIdx.x & 63;      // channel pair
  int rs = clampi(lower_bound_i(batch, N, g), 0, N);
  int re = clampi(lower_bound_i(batch, N, g + 1), rs, N);
  int len = re - rs;
  int a = rs + (int)(((long long)len * s) / POOL_S);
  int b = rs + (int)(((long long)len * (s + 1)) / POOL_S);
  float ax = 0.f, ay = 0.f;
  for (int i = a + h; i < b; i += 2){
    unsigned int u = x[(size_t)i*64 + lane];
    ax += __builtin_bit_cast(float, u << 16);
    ay += __builtin_bit_cast(float, u & 0xFFFF0000u);
  }
  float* p = partial + ((size_t)(g*POOL_S + s)*2 + h)*C_HID;
  p[2*lane]   = ax;
  p[2*lane+1] = ay;
}

// grid = NGRAPH blocks, 128 threads: reduce partials + linear head (fp32 out)
__global__ void k_final(const float* __restrict__ partial, const int* __restrict__ batch,
                        const float* __restrict__ Wl, const float* __restrict__ bl,
                        float* __restrict__ out, int N){
  __shared__ float sums[C_HID];
  int g = blockIdx.x;
  int t = threadIdx.x;
  float acc = 0.f;
  const float* p = partial + (size_t)g*POOL_S*2*C_HID;
  for (int j = 0; j < POOL_S*2; ++j)
    acc += p[j*C_HID + t];
  sums[t] = acc;
  __syncthreads();
  if (t < COUT){
    int rs = clampi(lower_bound_i(batch, N, g), 0, N);
    int re = clampi(lower_bound_i(batch, N, g + 1), rs, N);
    float inv = 1.0f / fmaxf((float)(re - rs), 1.0f);
    float o = 0.f;
    for (int k = 0; k < C_HID; ++k)
      o += sums[k] * Wl[k*COUT + t];
    out[g*COUT + t] = o * inv + bl[t];
  }
}

extern "C" void kernel_launch(void* const* d_in, const int* in_sizes, int n_in,
                              void* d_out, int out_size, void* d_ws, size_t ws_size,
                              hipStream_t stream){
  const float* x0 = (const float*)d_in[0];
  const int* ei   = (const int*)d_in[1];
  const int* batch= (const int*)d_in[2];
  const float* W1 = (const float*)d_in[3];
  const float* b1 = (const float*)d_in[4];
  const float* W2 = (const float*)d_in[5];
  const float* b2 = (const float*)d_in[6];
  const float* W3 = (const float*)d_in[7];
  const float* b3 = (const float*)d_in[8];
  const float* Wl = (const float*)d_in[9];
  const float* bl = (const float*)d_in[10];
  float* out = (float*)d_out;

  int E = in_sizes[1] / 2;
  int N = in_sizes[2];
  const int* src = ei;
  const int* dst = ei + E;

  // workspace layout (256B-aligned slots)
  size_t off_acc = 0;
  auto carve = [&](size_t bytes)->size_t{
    size_t r = off_acc; off_acc += (bytes + 255) & ~(size_t)255; return r;
  };
  size_t o_counts = carve((size_t)N*4);
  size_t o_cursor = carve((size_t)N*4);
  size_t o_offs   = carve((size_t)(N+1)*4);
  size_t o_bsum   = carve(256*4);
  size_t o_boff   = carve(256*4);
  size_t o_dinv   = carve((size_t)N*4);
  size_t o_srcs   = carve((size_t)E*4);
  size_t o_nrms   = carve((size_t)E*4);
  size_t o_aggb   = carve((size_t)N*C_HID*2);              // bf16
  size_t o_xbuf   = carve((size_t)N*C_HID*2);              // bf16
  size_t o_part   = carve((size_t)NGRAPH*POOL_S*2*C_HID*4); // fp32 partials (4 MB)
  size_t need = off_acc;

  if (ws_size < need){
    // diagnostic fallback: zero output (absmax would read exactly max|ref| = 1.167e-1)
    k_zero<<<(out_size+255)/256, 256, 0, stream>>>(out, out_size);
    return;
  }

  char* base = (char*)d_ws;
  int* counts   = (int*)(base + o_counts);
  int* cursor   = (int*)(base + o_cursor);
  int* offs     = (int*)(base + o_offs);
  int* bsum     = (int*)(base + o_bsum);
  int* boff     = (int*)(base + o_boff);
  float* dinv   = (float*)(base + o_dinv);
  int* src_s    = (int*)(base + o_srcs);
  float* nrm_s  = (float*)(base + o_nrms);
  unsigned int* aggb   = (unsigned int*)(base + o_aggb);
  unsigned short* xbuf = (unsigned short*)(base + o_xbuf);
  float* part   = (float*)(base + o_part);

  hipMemsetAsync(counts, 0, (size_t)N*4, stream);
  hipMemsetAsync(cursor, 0, (size_t)N*4, stream);

  int NB = (N + 511) / 512;
  k_hist <<<(E+255)/256, 256, 0, stream>>>(dst, counts, E, N);
  k_dinv <<<(N+255)/256, 256, 0, stream>>>(counts, dinv, N);
  k_scan1<<<NB, 512, 0, stream>>>(counts, bsum, N);
  k_scan2<<<1, 256, 0, stream>>>(bsum, boff, offs, NB, N);
  k_scan3<<<NB, 512, 0, stream>>>(counts, boff, offs, N);
  k_fill <<<(E+255)/256, 256, 0, stream>>>(src, dst, dinv, offs, cursor, src_s, nrm_s, E, N);

  int spmm_grid = (N + 3) / 4;     // 4 waves/block, one wave per node
  int gemm_grid = (N + 63) / 64;   // 64 rows/block

  k_spmm<true ><<<spmm_grid, 256, 0, stream>>>(x0, offs, src_s, nrm_s, dinv, aggb, N, E);
  k_gemm<<<gemm_grid, 256, 0, stream>>>((const unsigned short*)aggb, W1, b1, xbuf, N);
  k_spmm<false><<<spmm_grid, 256, 0, stream>>>(xbuf, offs, src_s, nrm_s, dinv, aggb, N, E);
  k_gemm<<<gemm_grid, 256, 0, stream>>>((const unsigned short*)aggb, W2, b2, xbuf, N);
  k_spmm<false><<<spmm_grid, 256, 0, stream>>>(xbuf, offs, src_s, nrm_s, dinv, aggb, N, E);
  k_gemm<<<gemm_grid, 256, 0, stream>>>((const unsigned short*)aggb, W3, b3, xbuf, N);

  k_pool <<<NGRAPH*POOL_S, 128, 0, stream>>>((const unsigned int*)xbuf, batch, part, N);
  k_final<<<NGRAPH, 128, 0, stream>>>(part, batch, Wl, bl, out, N);
}

// Round 5
// 592.839 us; speedup vs baseline: 2.0631x; 1.4205x over previous
//
#include <hip/hip_runtime.h>
#include <stdint.h>

#define C_HID 128
#define NGRAPH 64
#define COUT 64
#define POOL_S 64   // chunks per graph

typedef short bf16x8 __attribute__((ext_vector_type(8)));
typedef float f32x4 __attribute__((ext_vector_type(4)));

__device__ __forceinline__ float bf2f(unsigned short h){
  unsigned int u = ((unsigned int)h) << 16;
  return __builtin_bit_cast(float, u);
}
__device__ __forceinline__ unsigned short f2bf(float f){
  unsigned int u = __builtin_bit_cast(unsigned int, f);
  u = u + 0x7FFFu + ((u >> 16) & 1u);   // RNE
  return (unsigned short)(u >> 16);
}
__device__ __forceinline__ float bflo(unsigned int u){
  return __builtin_bit_cast(float, u << 16);
}
__device__ __forceinline__ float bfhi(unsigned int u){
  return __builtin_bit_cast(float, u & 0xFFFF0000u);
}
__device__ __forceinline__ int clampi(int v, int lo, int hi){
  return v < lo ? lo : (v > hi ? hi : v);
}

__global__ void k_zero(float* __restrict__ out, int n){
  int i = blockIdx.x*blockDim.x + threadIdx.x;
  if (i < n) out[i] = 0.f;
}

// ---------- CSR build ----------
__global__ void k_hist(const int* __restrict__ dst, int* __restrict__ counts, int E, int N){
  int e = blockIdx.x*blockDim.x + threadIdx.x;
  if (e < E) atomicAdd(&counts[clampi(dst[e], 0, N-1)], 1);
}

__global__ void k_dinv(const int* __restrict__ counts, float* __restrict__ dinv, int N){
  int i = blockIdx.x*blockDim.x + threadIdx.x;
  if (i < N) dinv[i] = rsqrtf((float)(counts[i] + 1));  // +1 = self loop
}

__global__ void k_scan1(const int* __restrict__ counts, int* __restrict__ bsum, int N){
  __shared__ int red[512];
  int i = blockIdx.x*512 + threadIdx.x;
  red[threadIdx.x] = (i < N) ? counts[i] : 0;
  __syncthreads();
  for (int off = 256; off > 0; off >>= 1){
    if (threadIdx.x < off) red[threadIdx.x] += red[threadIdx.x + off];
    __syncthreads();
  }
  if (threadIdx.x == 0) bsum[blockIdx.x] = red[0];
}

// single block, NB <= 256
__global__ void k_scan2(const int* __restrict__ bsum, int* __restrict__ boff,
                        int* __restrict__ offs, int NB, int N){
  __shared__ int buf[256];
  int t = threadIdx.x;
  int v = (t < NB) ? bsum[t] : 0;
  buf[t] = v; __syncthreads();
  for (int off = 1; off < 256; off <<= 1){
    int add = (t >= off) ? buf[t-off] : 0;
    __syncthreads();
    buf[t] += add;
    __syncthreads();
  }
  if (t < NB) boff[t] = buf[t] - v;          // exclusive
  if (t == NB-1) offs[N] = buf[t];           // total == E
}

__global__ void k_scan3(const int* __restrict__ counts, const int* __restrict__ boff,
                        int* __restrict__ offs, int N){
  __shared__ int buf[512];
  int t = threadIdx.x; int i = blockIdx.x*512 + t;
  int v = (i < N) ? counts[i] : 0;
  buf[t] = v; __syncthreads();
  for (int off = 1; off < 512; off <<= 1){
    int add = (t >= off) ? buf[t-off] : 0;
    __syncthreads();
    buf[t] += add;
    __syncthreads();
  }
  if (i < N) offs[i] = boff[blockIdx.x] + buf[t] - v;  // exclusive prefix
}

__global__ void k_fill(const int* __restrict__ src, const int* __restrict__ dst,
                       const float* __restrict__ dinv, const int* __restrict__ offs,
                       int* __restrict__ cursor, int* __restrict__ src_s,
                       float* __restrict__ nrm_s, int E, int N){
  int e = blockIdx.x*blockDim.x + threadIdx.x;
  if (e >= E) return;
  int d = clampi(dst[e], 0, N-1);
  int s = clampi(src[e], 0, N-1);
  int pos = offs[d] + atomicAdd(&cursor[d], 1);
  pos = clampi(pos, 0, E-1);
  src_s[pos] = s;
  nrm_s[pos] = dinv[s] * dinv[d];
}

// ---------- x0 fp32 -> packed bf16 ----------
__global__ void k_xcast(const float2* __restrict__ x, unsigned int* __restrict__ o, long long n2){
  long long i = (long long)blockIdx.x*blockDim.x + threadIdx.x;
  if (i < n2){
    float2 v = x[i];
    o[i] = (unsigned int)f2bf(v.x) | ((unsigned int)f2bf(v.y) << 16);
  }
}

// ---------- W fp32 [128][128] -> Wt bf16 [n][k] (3 weights) ----------
__global__ void k_prep(const float* __restrict__ W1, const float* __restrict__ W2,
                       const float* __restrict__ W3, unsigned short* __restrict__ Wt){
  int idx = blockIdx.x*256 + threadIdx.x;     // grid = 192 blocks
  int w = idx >> 14;                           // 16384 per weight
  int r = idx & 16383;
  int n = r & 127, k = r >> 7;
  const float* W = (w == 0) ? W1 : (w == 1) ? W2 : W3;
  Wt[(size_t)w*16384 + (size_t)n*128 + k] = f2bf(W[k*128 + n]);
}

// ---------- SpMM: agg[i] = sum_e norm_e * x[src_e] + dinv[i]^2 * x[i] ----------
// one wave per node; lane owns channels (2*lane, 2*lane+1) packed bf16.
// unroll-4 with clamp+zero-weight predication -> 4 gathers in flight.
__global__ void k_spmm(const unsigned int* __restrict__ x, const int* __restrict__ offs,
                       const int* __restrict__ srcs, const float* __restrict__ nrms,
                       const float* __restrict__ dinv, unsigned int* __restrict__ agg,
                       int N){
  int gid = blockIdx.x*blockDim.x + threadIdx.x;
  int node = gid >> 6;
  int lane = gid & 63;
  if (node >= N) return;
  int e0 = offs[node], e1 = offs[node+1];
  float ax = 0.f, ay = 0.f;
  for (int e = e0; e < e1; e += 4){
    int i1 = (e+1 < e1) ? e+1 : e;
    int i2 = (e+2 < e1) ? e+2 : e;
    int i3 = (e+3 < e1) ? e+3 : e;
    int s0 = srcs[e],  s1 = srcs[i1], s2 = srcs[i2], s3 = srcs[i3];
    float n0 = nrms[e];
    float n1 = (e+1 < e1) ? nrms[i1] : 0.f;
    float n2 = (e+2 < e1) ? nrms[i2] : 0.f;
    float n3 = (e+3 < e1) ? nrms[i3] : 0.f;
    unsigned int u0 = x[(size_t)s0*64 + lane];
    unsigned int u1 = x[(size_t)s1*64 + lane];
    unsigned int u2 = x[(size_t)s2*64 + lane];
    unsigned int u3 = x[(size_t)s3*64 + lane];
    ax += n0*bflo(u0) + n1*bflo(u1) + n2*bflo(u2) + n3*bflo(u3);
    ay += n0*bfhi(u0) + n1*bfhi(u1) + n2*bfhi(u2) + n3*bfhi(u3);
  }
  float di = dinv[node];
  float nr = di * di;                // self loop
  unsigned int u = x[(size_t)node*64 + lane];
  ax += nr * bflo(u);
  ay += nr * bfhi(u);
  agg[(size_t)node*64 + lane] = (unsigned int)f2bf(ax) | ((unsigned int)f2bf(ay) << 16);
}

// ---------- GEMM: out = relu(A[Mx128] @ W[128x128] + b) ----------
// A: bf16 [M][128]; Wt: bf16 [n][k]; b: fp32; out: bf16.
// block = 4 waves, 64 rows/block; Wt staged to LDS stride 136 (benign 2-way conflicts)
__global__ __launch_bounds__(256) void k_gemm(const unsigned short* __restrict__ A,
                                              const unsigned short* __restrict__ Wt,
                                              const float* __restrict__ bias,
                                              unsigned short* __restrict__ out, int M){
  __shared__ unsigned short wt[128*136];
  {
    const uint4* wsrc = (const uint4*)Wt;     // 4096 uint4 (8 shorts each)
    for (int i = threadIdx.x; i < 4096; i += 256){
      uint4 v = wsrc[i];
      int n = i >> 4, kblk = i & 15;          // row = 16 uint4
      *(uint4*)&wt[n*136 + kblk*8] = v;
    }
  }
  __syncthreads();

  int wv = threadIdx.x >> 6, lane = threadIdx.x & 63;
  int q = lane >> 4, ln = lane & 15;
  int m0 = blockIdx.x*64 + wv*16;
  int arow = m0 + ln;
  bool arow_ok = (arow < M);
  if (!arow_ok) arow = 0;            // safe address; fragment zeroed below

  f32x4 zero = {0.f, 0.f, 0.f, 0.f};
  f32x4 acc[8];
  #pragma unroll
  for (int t = 0; t < 8; ++t) acc[t] = zero;

  #pragma unroll
  for (int kk = 0; kk < 4; ++kk){
    // A-frag: A[m = lane&15][k = kk*32 + q*8 + j]
    bf16x8 a;
    if (arow_ok){
      __builtin_memcpy(&a, A + (size_t)arow*128 + kk*32 + q*8, 16);
    } else {
      a = (bf16x8){0,0,0,0,0,0,0,0};
    }
    #pragma unroll
    for (int t = 0; t < 8; ++t){
      // B-frag: B[k][n = t*16 + ln] == Wt[n][k], contiguous in k
      bf16x8 b;
      __builtin_memcpy(&b, &wt[(t*16 + ln)*136 + kk*32 + q*8], 16);
      acc[t] = __builtin_amdgcn_mfma_f32_16x16x32_bf16(a, b, acc[t], 0, 0, 0);
    }
  }
  // D: row = m0 + q*4 + r, col = t*16 + ln
  #pragma unroll
  for (int t = 0; t < 8; ++t){
    float bv = bias[t*16 + ln];
    #pragma unroll
    for (int r = 0; r < 4; ++r){
      int row = m0 + q*4 + r;
      if (row < M){
        float v = acc[t][r] + bv;
        v = v > 0.f ? v : 0.f;
        out[(size_t)row*128 + t*16 + ln] = f2bf(v);
      }
    }
  }
}

// ---------- pooling ----------
__device__ __forceinline__ int lower_bound_i(const int* arr, int n, int val){
  int lo = 0, hi = n;
  while (lo < hi){ int mid = (lo + hi) >> 1; if (arr[mid] < val) lo = mid + 1; else hi = mid; }
  return lo;
}

// grid = NGRAPH*POOL_S blocks, 128 threads.
__global__ void k_pool(const unsigned int* __restrict__ x, const int* __restrict__ batch,
                       float* __restrict__ partial, int N){
  int g = blockIdx.x / POOL_S, s = blockIdx.x % POOL_S;
  int h = threadIdx.x >> 6;         // 0/1
  int lane = threadIdx.x & 63;      // channel pair
  int rs = clampi(lower_bound_i(batch, N, g), 0, N);
  int re = clampi(lower_bound_i(batch, N, g + 1), rs, N);
  int len = re - rs;
  int a = rs + (int)(((long long)len * s) / POOL_S);
  int b = rs + (int)(((long long)len * (s + 1)) / POOL_S);
  float ax = 0.f, ay = 0.f;
  for (int i = a + h; i < b; i += 2){
    unsigned int u = x[(size_t)i*64 + lane];
    ax += bflo(u);
    ay += bfhi(u);
  }
  float* p = partial + ((size_t)(g*POOL_S + s)*2 + h)*C_HID;
  p[2*lane]   = ax;
  p[2*lane+1] = ay;
}

// grid = NGRAPH blocks, 128 threads: reduce partials + linear head (fp32 out)
__global__ void k_final(const float* __restrict__ partial, const int* __restrict__ batch,
                        const float* __restrict__ Wl, const float* __restrict__ bl,
                        float* __restrict__ out, int N){
  __shared__ float sums[C_HID];
  int g = blockIdx.x;
  int t = threadIdx.x;
  float acc = 0.f;
  const float* p = partial + (size_t)g*POOL_S*2*C_HID;
  for (int j = 0; j < POOL_S*2; ++j)
    acc += p[j*C_HID + t];
  sums[t] = acc;
  __syncthreads();
  if (t < COUT){
    int rs = clampi(lower_bound_i(batch, N, g), 0, N);
    int re = clampi(lower_bound_i(batch, N, g + 1), rs, N);
    float inv = 1.0f / fmaxf((float)(re - rs), 1.0f);
    float o = 0.f;
    for (int k = 0; k < C_HID; ++k)
      o += sums[k] * Wl[k*COUT + t];
    out[g*COUT + t] = o * inv + bl[t];
  }
}

extern "C" void kernel_launch(void* const* d_in, const int* in_sizes, int n_in,
                              void* d_out, int out_size, void* d_ws, size_t ws_size,
                              hipStream_t stream){
  const float* x0 = (const float*)d_in[0];
  const int* ei   = (const int*)d_in[1];
  const int* batch= (const int*)d_in[2];
  const float* W1 = (const float*)d_in[3];
  const float* b1 = (const float*)d_in[4];
  const float* W2 = (const float*)d_in[5];
  const float* b2 = (const float*)d_in[6];
  const float* W3 = (const float*)d_in[7];
  const float* b3 = (const float*)d_in[8];
  const float* Wl = (const float*)d_in[9];
  const float* bl = (const float*)d_in[10];
  float* out = (float*)d_out;

  int E = in_sizes[1] / 2;
  int N = in_sizes[2];
  const int* src = ei;
  const int* dst = ei + E;

  // workspace layout (256B-aligned slots)
  size_t off_acc = 0;
  auto carve = [&](size_t bytes)->size_t{
    size_t r = off_acc; off_acc += (bytes + 255) & ~(size_t)255; return r;
  };
  size_t o_counts = carve((size_t)N*4);
  size_t o_cursor = carve((size_t)N*4);
  size_t o_offs   = carve((size_t)(N+1)*4);
  size_t o_bsum   = carve(256*4);
  size_t o_boff   = carve(256*4);
  size_t o_dinv   = carve((size_t)N*4);
  size_t o_srcs   = carve((size_t)E*4);
  size_t o_nrms   = carve((size_t)E*4);
  size_t o_aggb   = carve((size_t)N*C_HID*2);               // bf16 ping
  size_t o_xbuf   = carve((size_t)N*C_HID*2);               // bf16 pong (also x0-bf16)
  size_t o_part   = carve((size_t)NGRAPH*POOL_S*2*C_HID*4); // fp32 partials (4 MB)
  size_t o_wt     = carve((size_t)3*128*128*2);             // bf16 Wt x3
  size_t need = off_acc;

  if (ws_size < need){
    // diagnostic fallback: zero output (absmax would read exactly max|ref| = 1.167e-1)
    k_zero<<<(out_size+255)/256, 256, 0, stream>>>(out, out_size);
    return;
  }

  char* base = (char*)d_ws;
  int* counts   = (int*)(base + o_counts);
  int* cursor   = (int*)(base + o_cursor);
  int* offs     = (int*)(base + o_offs);
  int* bsum     = (int*)(base + o_bsum);
  int* boff     = (int*)(base + o_boff);
  float* dinv   = (float*)(base + o_dinv);
  int* src_s    = (int*)(base + o_srcs);
  float* nrm_s  = (float*)(base + o_nrms);
  unsigned int* aggb   = (unsigned int*)(base + o_aggb);
  unsigned int* xbuf   = (unsigned int*)(base + o_xbuf);
  float* part   = (float*)(base + o_part);
  unsigned short* wt   = (unsigned short*)(base + o_wt);

  hipMemsetAsync(counts, 0, (size_t)N*4, stream);
  hipMemsetAsync(cursor, 0, (size_t)N*4, stream);

  int NB = (N + 511) / 512;
  k_hist <<<(E+255)/256, 256, 0, stream>>>(dst, counts, E, N);
  k_dinv <<<(N+255)/256, 256, 0, stream>>>(counts, dinv, N);
  k_scan1<<<NB, 512, 0, stream>>>(counts, bsum, N);
  k_scan2<<<1, 256, 0, stream>>>(bsum, boff, offs, NB, N);
  k_scan3<<<NB, 512, 0, stream>>>(counts, boff, offs, N);
  k_fill <<<(E+255)/256, 256, 0, stream>>>(src, dst, dinv, offs, cursor, src_s, nrm_s, E, N);

  long long n2 = (long long)N * 64;
  k_xcast<<<(int)((n2 + 255)/256), 256, 0, stream>>>((const float2*)x0, xbuf, n2);
  k_prep <<<192, 256, 0, stream>>>(W1, W2, W3, wt);

  int spmm_grid = (N + 3) / 4;     // 4 waves/block, one wave per node
  int gemm_grid = (N + 63) / 64;   // 64 rows/block

  k_spmm<<<spmm_grid, 256, 0, stream>>>(xbuf, offs, src_s, nrm_s, dinv, aggb, N);
  k_gemm<<<gemm_grid, 256, 0, stream>>>((const unsigned short*)aggb, wt,           b1, (unsigned short*)xbuf, N);
  k_spmm<<<spmm_grid, 256, 0, stream>>>(xbuf, offs, src_s, nrm_s, dinv, aggb, N);
  k_gemm<<<gemm_grid, 256, 0, stream>>>((const unsigned short*)aggb, wt + 16384,   b2, (unsigned short*)xbuf, N);
  k_spmm<<<spmm_grid, 256, 0, stream>>>(xbuf, offs, src_s, nrm_s, dinv, aggb, N);
  k_gemm<<<gemm_grid, 256, 0, stream>>>((const unsigned short*)aggb, wt + 2*16384, b3, (unsigned short*)xbuf, N);

  k_pool <<<NGRAPH*POOL_S, 128, 0, stream>>>(xbuf, batch, part, N);
  k_final<<<NGRAPH, 128, 0, stream>>>(part, batch, Wl, bl, out, N);
}

// Round 6
// 582.375 us; speedup vs baseline: 2.1002x; 1.0180x over previous
//
#include <hip/hip_runtime.h>
#include <stdint.h>

#define C_HID 128
#define NGRAPH 64
#define COUT 64
#define POOL_S 64   // chunks per graph

typedef short bf16x8 __attribute__((ext_vector_type(8)));
typedef float f32x4 __attribute__((ext_vector_type(4)));

__device__ __forceinline__ float bf2f(unsigned short h){
  unsigned int u = ((unsigned int)h) << 16;
  return __builtin_bit_cast(float, u);
}
__device__ __forceinline__ unsigned short f2bf(float f){
  unsigned int u = __builtin_bit_cast(unsigned int, f);
  u = u + 0x7FFFu + ((u >> 16) & 1u);   // RNE
  return (unsigned short)(u >> 16);
}
__device__ __forceinline__ float bflo(unsigned int u){
  return __builtin_bit_cast(float, u << 16);
}
__device__ __forceinline__ float bfhi(unsigned int u){
  return __builtin_bit_cast(float, u & 0xFFFF0000u);
}
__device__ __forceinline__ int clampi(int v, int lo, int hi){
  return v < lo ? lo : (v > hi ? hi : v);
}

__global__ void k_zero(float* __restrict__ out, int n){
  int i = blockIdx.x*blockDim.x + threadIdx.x;
  if (i < n) out[i] = 0.f;
}

// ---------- CSR build ----------
__global__ void k_hist(const int* __restrict__ dst, int* __restrict__ counts, int E, int N){
  int e = blockIdx.x*blockDim.x + threadIdx.x;
  if (e < E) atomicAdd(&counts[clampi(dst[e], 0, N-1)], 1);
}

__global__ void k_dinv(const int* __restrict__ counts, float* __restrict__ dinv, int N){
  int i = blockIdx.x*blockDim.x + threadIdx.x;
  if (i < N) dinv[i] = rsqrtf((float)(counts[i] + 1));  // +1 = self loop
}

__global__ void k_scan1(const int* __restrict__ counts, int* __restrict__ bsum, int N){
  __shared__ int red[512];
  int i = blockIdx.x*512 + threadIdx.x;
  red[threadIdx.x] = (i < N) ? counts[i] : 0;
  __syncthreads();
  for (int off = 256; off > 0; off >>= 1){
    if (threadIdx.x < off) red[threadIdx.x] += red[threadIdx.x + off];
    __syncthreads();
  }
  if (threadIdx.x == 0) bsum[blockIdx.x] = red[0];
}

// single block, NB <= 256
__global__ void k_scan2(const int* __restrict__ bsum, int* __restrict__ boff,
                        int* __restrict__ offs, int NB, int N){
  __shared__ int buf[256];
  int t = threadIdx.x;
  int v = (t < NB) ? bsum[t] : 0;
  buf[t] = v; __syncthreads();
  for (int off = 1; off < 256; off <<= 1){
    int add = (t >= off) ? buf[t-off] : 0;
    __syncthreads();
    buf[t] += add;
    __syncthreads();
  }
  if (t < NB) boff[t] = buf[t] - v;          // exclusive
  if (t == NB-1) offs[N] = buf[t];           // total == E
}

__global__ void k_scan3(const int* __restrict__ counts, const int* __restrict__ boff,
                        int* __restrict__ offs, int N){
  __shared__ int buf[512];
  int t = threadIdx.x; int i = blockIdx.x*512 + t;
  int v = (i < N) ? counts[i] : 0;
  buf[t] = v; __syncthreads();
  for (int off = 1; off < 512; off <<= 1){
    int add = (t >= off) ? buf[t-off] : 0;
    __syncthreads();
    buf[t] += add;
    __syncthreads();
  }
  if (i < N) offs[i] = boff[blockIdx.x] + buf[t] - v;  // exclusive prefix
}

// meta[pos] = {src, norm} as one 8B store (halves scattered dirty lines vs 2x4B)
__global__ void k_fill(const int* __restrict__ src, const int* __restrict__ dst,
                       const float* __restrict__ dinv, const int* __restrict__ offs,
                       int* __restrict__ cursor, uint2* __restrict__ meta,
                       int E, int N){
  int e = blockIdx.x*blockDim.x + threadIdx.x;
  if (e >= E) return;
  int d = clampi(dst[e], 0, N-1);
  int s = clampi(src[e], 0, N-1);
  int pos = offs[d] + atomicAdd(&cursor[d], 1);
  pos = clampi(pos, 0, E-1);
  uint2 m;
  m.x = (unsigned int)s;
  m.y = __builtin_bit_cast(unsigned int, dinv[s] * dinv[d]);
  meta[pos] = m;
}

// ---------- x0 fp32 -> packed bf16 ----------
__global__ void k_xcast(const float2* __restrict__ x, unsigned int* __restrict__ o, long long n2){
  long long i = (long long)blockIdx.x*blockDim.x + threadIdx.x;
  if (i < n2){
    float2 v = x[i];
    o[i] = (unsigned int)f2bf(v.x) | ((unsigned int)f2bf(v.y) << 16);
  }
}

// ---------- W fp32 [128][128] -> Wt bf16 [n][k] (3 weights) ----------
__global__ void k_prep(const float* __restrict__ W1, const float* __restrict__ W2,
                       const float* __restrict__ W3, unsigned short* __restrict__ Wt){
  int idx = blockIdx.x*256 + threadIdx.x;     // grid = 192 blocks
  int w = idx >> 14;                           // 16384 per weight
  int r = idx & 16383;
  int n = r & 127, k = r >> 7;
  const float* W = (w == 0) ? W1 : (w == 1) ? W2 : W3;
  Wt[(size_t)w*16384 + (size_t)n*128 + k] = f2bf(W[k*128 + n]);
}

// ---------- SpMM: agg[i] = sum_e norm_e * x[src_e] + dinv[i]^2 * x[i] ----------
// one wave per node; lane owns channels (2*lane, 2*lane+1) packed bf16.
// unroll-8 with clamp+zero-weight predication -> 8 gathers in flight.
__global__ void k_spmm(const unsigned int* __restrict__ x, const int* __restrict__ offs,
                       const uint2* __restrict__ meta, const float* __restrict__ dinv,
                       unsigned int* __restrict__ agg, int N){
  int gid = blockIdx.x*blockDim.x + threadIdx.x;
  int node = gid >> 6;
  int lane = gid & 63;
  if (node >= N) return;
  int e0 = offs[node], e1 = offs[node+1];
  float ax = 0.f, ay = 0.f;
  for (int e = e0; e < e1; e += 8){
    int idx[8]; uint2 m[8]; float n[8]; unsigned int u[8];
    #pragma unroll
    for (int j = 0; j < 8; ++j){
      int ej = e + j;
      idx[j] = (ej < e1) ? ej : (e1 - 1);
      m[j] = meta[idx[j]];
    }
    #pragma unroll
    for (int j = 0; j < 8; ++j){
      n[j] = (e + j < e1) ? __builtin_bit_cast(float, m[j].y) : 0.f;
      u[j] = x[(size_t)m[j].x*64 + lane];
    }
    #pragma unroll
    for (int j = 0; j < 8; ++j){
      ax += n[j] * bflo(u[j]);
      ay += n[j] * bfhi(u[j]);
    }
  }
  float di = dinv[node];
  float nr = di * di;                // self loop
  unsigned int u = x[(size_t)node*64 + lane];
  ax += nr * bflo(u);
  ay += nr * bfhi(u);
  agg[(size_t)node*64 + lane] = (unsigned int)f2bf(ax) | ((unsigned int)f2bf(ay) << 16);
}

// ---------- GEMM: out = relu(A[Mx128] @ W[128x128] + b) ----------
// A: bf16 [M][128]; Wt: bf16 [n][k]; b: fp32; out: bf16.
// Grid-stride over 64-row tiles: W staged to LDS ONCE per block, reused across tiles.
#define GEMM_BLOCKS 512
__global__ __launch_bounds__(256) void k_gemm(const unsigned short* __restrict__ A,
                                              const unsigned short* __restrict__ Wt,
                                              const float* __restrict__ bias,
                                              unsigned short* __restrict__ out, int M){
  __shared__ unsigned short wt[128*136];
  {
    const uint4* wsrc = (const uint4*)Wt;     // 4096 uint4 (8 shorts each)
    for (int i = threadIdx.x; i < 4096; i += 256){
      uint4 v = wsrc[i];
      int n = i >> 4, kblk = i & 15;          // row = 16 uint4
      *(uint4*)&wt[n*136 + kblk*8] = v;
    }
  }
  __syncthreads();

  int wv = threadIdx.x >> 6, lane = threadIdx.x & 63;
  int q = lane >> 4, ln = lane & 15;
  int tiles = (M + 63) >> 6;

  for (int tile = blockIdx.x; tile < tiles; tile += GEMM_BLOCKS){
    int m0 = tile*64 + wv*16;
    int arow = m0 + ln;
    bool arow_ok = (arow < M);
    int arow_s = arow_ok ? arow : 0;

    f32x4 zero = {0.f, 0.f, 0.f, 0.f};
    f32x4 acc[8];
    #pragma unroll
    for (int t = 0; t < 8; ++t) acc[t] = zero;

    #pragma unroll
    for (int kk = 0; kk < 4; ++kk){
      // A-frag: A[m = lane&15][k = kk*32 + q*8 + j]
      bf16x8 a;
      if (arow_ok){
        __builtin_memcpy(&a, A + (size_t)arow_s*128 + kk*32 + q*8, 16);
      } else {
        a = (bf16x8){0,0,0,0,0,0,0,0};
      }
      #pragma unroll
      for (int t = 0; t < 8; ++t){
        // B-frag: B[k][n = t*16 + ln] == Wt[n][k], contiguous in k
        bf16x8 b;
        __builtin_memcpy(&b, &wt[(t*16 + ln)*136 + kk*32 + q*8], 16);
        acc[t] = __builtin_amdgcn_mfma_f32_16x16x32_bf16(a, b, acc[t], 0, 0, 0);
      }
    }
    // D: row = m0 + q*4 + r, col = t*16 + ln
    #pragma unroll
    for (int t = 0; t < 8; ++t){
      float bv = bias[t*16 + ln];
      #pragma unroll
      for (int r = 0; r < 4; ++r){
        int row = m0 + q*4 + r;
        if (row < M){
          float v = acc[t][r] + bv;
          v = v > 0.f ? v : 0.f;
          out[(size_t)row*128 + t*16 + ln] = f2bf(v);
        }
      }
    }
  }
}

// ---------- pooling ----------
__device__ __forceinline__ int lower_bound_i(const int* arr, int n, int val){
  int lo = 0, hi = n;
  while (lo < hi){ int mid = (lo + hi) >> 1; if (arr[mid] < val) lo = mid + 1; else hi = mid; }
  return lo;
}

// grid = NGRAPH*POOL_S blocks, 128 threads.
__global__ void k_pool(const unsigned int* __restrict__ x, const int* __restrict__ batch,
                       float* __restrict__ partial, int N){
  int g = blockIdx.x / POOL_S, s = blockIdx.x % POOL_S;
  int h = threadIdx.x >> 6;         // 0/1
  int lane = threadIdx.x & 63;      // channel pair
  int rs = clampi(lower_bound_i(batch, N, g), 0, N);
  int re = clampi(lower_bound_i(batch, N, g + 1), rs, N);
  int len = re - rs;
  int a = rs + (int)(((long long)len * s) / POOL_S);
  int b = rs + (int)(((long long)len * (s + 1)) / POOL_S);
  float ax = 0.f, ay = 0.f;
  for (int i = a + h; i < b; i += 2){
    unsigned int u = x[(size_t)i*64 + lane];
    ax += bflo(u);
    ay += bfhi(u);
  }
  float* p = partial + ((size_t)(g*POOL_S + s)*2 + h)*C_HID;
  p[2*lane]   = ax;
  p[2*lane+1] = ay;
}

// grid = NGRAPH blocks, 128 threads: reduce partials + linear head (fp32 out)
__global__ void k_final(const float* __restrict__ partial, const int* __restrict__ batch,
                        const float* __restrict__ Wl, const float* __restrict__ bl,
                        float* __restrict__ out, int N){
  __shared__ float sums[C_HID];
  int g = blockIdx.x;
  int t = threadIdx.x;
  float acc = 0.f;
  const float* p = partial + (size_t)g*POOL_S*2*C_HID;
  for (int j = 0; j < POOL_S*2; ++j)
    acc += p[j*C_HID + t];
  sums[t] = acc;
  __syncthreads();
  if (t < COUT){
    int rs = clampi(lower_bound_i(batch, N, g), 0, N);
    int re = clampi(lower_bound_i(batch, N, g + 1), rs, N);
    float inv = 1.0f / fmaxf((float)(re - rs), 1.0f);
    float o = 0.f;
    for (int k = 0; k < 128; ++k)
      o += sums[k] * Wl[k*COUT + t];
    out[g*COUT + t] = o * inv + bl[t];
  }
}

extern "C" void kernel_launch(void* const* d_in, const int* in_sizes, int n_in,
                              void* d_out, int out_size, void* d_ws, size_t ws_size,
                              hipStream_t stream){
  const float* x0 = (const float*)d_in[0];
  const int* ei   = (const int*)d_in[1];
  const int* batch= (const int*)d_in[2];
  const float* W1 = (const float*)d_in[3];
  const float* b1 = (const float*)d_in[4];
  const float* W2 = (const float*)d_in[5];
  const float* b2 = (const float*)d_in[6];
  const float* W3 = (const float*)d_in[7];
  const float* b3 = (const float*)d_in[8];
  const float* Wl = (const float*)d_in[9];
  const float* bl = (const float*)d_in[10];
  float* out = (float*)d_out;

  int E = in_sizes[1] / 2;
  int N = in_sizes[2];
  const int* src = ei;
  const int* dst = ei + E;

  // workspace layout (256B-aligned slots)
  size_t off_acc = 0;
  auto carve = [&](size_t bytes)->size_t{
    size_t r = off_acc; off_acc += (bytes + 255) & ~(size_t)255; return r;
  };
  size_t o_counts = carve((size_t)N*4);
  size_t o_cursor = carve((size_t)N*4);
  size_t o_offs   = carve((size_t)(N+1)*4);
  size_t o_bsum   = carve(256*4);
  size_t o_boff   = carve(256*4);
  size_t o_dinv   = carve((size_t)N*4);
  size_t o_meta   = carve((size_t)E*8);                     // {src, nrm} pairs
  size_t o_aggb   = carve((size_t)N*C_HID*2);               // bf16 ping
  size_t o_xbuf   = carve((size_t)N*C_HID*2);               // bf16 pong (also x0-bf16)
  size_t o_part   = carve((size_t)NGRAPH*POOL_S*2*C_HID*4); // fp32 partials (4 MB)
  size_t o_wt     = carve((size_t)3*128*128*2);             // bf16 Wt x3
  size_t need = off_acc;

  if (ws_size < need){
    // diagnostic fallback: zero output (absmax would read exactly max|ref| = 1.167e-1)
    k_zero<<<(out_size+255)/256, 256, 0, stream>>>(out, out_size);
    return;
  }

  char* base = (char*)d_ws;
  int* counts   = (int*)(base + o_counts);
  int* cursor   = (int*)(base + o_cursor);
  int* offs     = (int*)(base + o_offs);
  int* bsum     = (int*)(base + o_bsum);
  int* boff     = (int*)(base + o_boff);
  float* dinv   = (float*)(base + o_dinv);
  uint2* meta   = (uint2*)(base + o_meta);
  unsigned int* aggb   = (unsigned int*)(base + o_aggb);
  unsigned int* xbuf   = (unsigned int*)(base + o_xbuf);
  float* part   = (float*)(base + o_part);
  unsigned short* wt   = (unsigned short*)(base + o_wt);

  hipMemsetAsync(counts, 0, (size_t)N*4, stream);
  hipMemsetAsync(cursor, 0, (size_t)N*4, stream);

  int NB = (N + 511) / 512;
  k_hist <<<(E+255)/256, 256, 0, stream>>>(dst, counts, E, N);
  k_dinv <<<(N+255)/256, 256, 0, stream>>>(counts, dinv, N);
  k_scan1<<<NB, 512, 0, stream>>>(counts, bsum, N);
  k_scan2<<<1, 256, 0, stream>>>(bsum, boff, offs, NB, N);
  k_scan3<<<NB, 512, 0, stream>>>(counts, boff, offs, N);
  k_fill <<<(E+255)/256, 256, 0, stream>>>(src, dst, dinv, offs, cursor, meta, E, N);

  long long n2 = (long long)N * 64;
  k_xcast<<<(int)((n2 + 255)/256), 256, 0, stream>>>((const float2*)x0, xbuf, n2);
  k_prep <<<192, 256, 0, stream>>>(W1, W2, W3, wt);

  int spmm_grid = (N + 3) / 4;     // 4 waves/block, one wave per node

  k_spmm<<<spmm_grid, 256, 0, stream>>>(xbuf, offs, meta, dinv, aggb, N);
  k_gemm<<<GEMM_BLOCKS, 256, 0, stream>>>((const unsigned short*)aggb, wt,           b1, (unsigned short*)xbuf, N);
  k_spmm<<<spmm_grid, 256, 0, stream>>>(xbuf, offs, meta, dinv, aggb, N);
  k_gemm<<<GEMM_BLOCKS, 256, 0, stream>>>((const unsigned short*)aggb, wt + 16384,   b2, (unsigned short*)xbuf, N);
  k_spmm<<<spmm_grid, 256, 0, stream>>>(xbuf, offs, meta, dinv, aggb, N);
  k_gemm<<<GEMM_BLOCKS, 256, 0, stream>>>((const unsigned short*)aggb, wt + 2*16384, b3, (unsigned short*)xbuf, N);

  k_pool <<<NGRAPH*POOL_S, 128, 0, stream>>>(xbuf, batch, part, N);
  k_final<<<NGRAPH, 128, 0, stream>>>(part, batch, Wl, bl, out, N);
}